// Round 1
// baseline (490.337 us; speedup 1.0000x reference)
//
#include <hip/hip_runtime.h>
#include <hip/hip_bf16.h>
#include <cstdint>

// Varkeys: out[b,c] = sum_d values[d,c] / (||k_d||^2 - 2 k_d.x_b + ||x_b||^2 + EPS)
// Fused flash-style: per WG, loop dict tiles: MFMA scores -> rcp -> MFMA with values.
// B=4096 D=16384 K=512 C=100. bf16 MFMA 16x16x32, fp32 accum.

#define BSZ   4096
#define DSZ   16384
#define KSZ   512
#define CC    100
#define EPSV  1e-4f

#define BM     128          // batch rows per WG
#define BD     64           // dict rows per iter
#define DSPLIT 16
#define DCHUNK (DSZ / DSPLIT)   // 1024
#define NITER  (DCHUNK / BD)    // 16
#define KC     64               // k staging chunk
#define NKC    (KSZ / KC)       // 8

#define XS_STRIDE 72   // bf16 elems (pad 8) -> 144B rows, 16B aligned
#define KS_STRIDE 72
#define KT_STRIDE 72
#define VL_STRIDE 106  // odd dword stride (53) -> conflict-free u16 col reads

typedef short  short8 __attribute__((ext_vector_type(8)));
typedef float  f32x4  __attribute__((ext_vector_type(4)));

__device__ __forceinline__ unsigned short f2bf(float f) {
    union { float f; unsigned u; } cv; cv.f = f;
    unsigned u = cv.u;
    u += 0x7fffu + ((u >> 16) & 1u);   // RNE
    return (unsigned short)(u >> 16);
}
__device__ __forceinline__ unsigned pack2(float a, float b) {
    return (unsigned)f2bf(a) | ((unsigned)f2bf(b) << 16);
}

// --- pre-kernel: kk[d] = ||keys_d||^2, xx[b] = ||x_b||^2 (ws path) ---
__global__ __launch_bounds__(256)
void varkeys_pre(const float* __restrict__ x, const float* __restrict__ keys,
                 float* __restrict__ kk, float* __restrict__ xx)
{
    const int tid  = threadIdx.x;
    const int wid  = tid >> 6;
    const int lane = tid & 63;
    const int lo   = lane & 15;
    const int sub  = lane >> 4;
    const int row  = blockIdx.x * 16 + wid * 4 + sub;  // 0..20479
    const float* src = (row < DSZ) ? keys + (size_t)row * KSZ
                                   : x + (size_t)(row - DSZ) * KSZ;
    float s = 0.f;
#pragma unroll
    for (int j = 0; j < 8; ++j) {
        float4 v = *reinterpret_cast<const float4*>(src + j * 64 + lo * 4);
        s += v.x * v.x + v.y * v.y + v.z * v.z + v.w * v.w;
    }
    s += __shfl_xor(s, 1); s += __shfl_xor(s, 2);
    s += __shfl_xor(s, 4); s += __shfl_xor(s, 8);
    if (lo == 0) {
        if (row < DSZ) kk[row] = s;
        else           xx[row - DSZ] = s;
    }
}

// --- main fused kernel ---
__global__ __launch_bounds__(256, 2)
void varkeys_main(const float* __restrict__ x, const float* __restrict__ keys,
                  const float* __restrict__ values, float* __restrict__ out,
                  const float* __restrict__ kk_ws, const float* __restrict__ xx_ws,
                  int use_ws)
{
    __shared__ __align__(16) unsigned short xs[BM * XS_STRIDE];
    __shared__ __align__(16) unsigned short ks[BD * KS_STRIDE];
    __shared__ __align__(16) unsigned short kT[BM * KT_STRIDE];   // kern[batch][dict] bf16
    __shared__ __align__(16) unsigned short vls[BD * VL_STRIDE];  // values[dict][c] bf16
    __shared__ float kk_s[DCHUNK];
    __shared__ float xx_s[BM];

    const int tid  = threadIdx.x;
    const int wid  = tid >> 6;
    const int lane = tid & 63;
    const int lo   = lane & 15;
    const int hi   = lane >> 4;
    const int wm   = wid >> 1;   // batch half: rows wm*64..+63
    const int wn   = wid & 1;    // phase A dict half (wn*32), phase B col half (wn*64)
    const int bm0   = blockIdx.x * BM;
    const int dbase = blockIdx.y * DCHUNK;

    // ---- prologue: kk_s / xx_s ----
    if (use_ws) {
        for (int i = tid; i < DCHUNK; i += 256) kk_s[i] = kk_ws[dbase + i];
        if (tid < BM) xx_s[tid] = xx_ws[bm0 + tid];
    } else {
        // rows 0..1023 -> keys[dbase+row]; rows 1024..1151 -> x[bm0+row-1024]
        for (int rbase = wid * 4; rbase < DCHUNK + BM; rbase += 16) {
            const int row = rbase + hi;
            const float* src = (row < DCHUNK)
                ? keys + (size_t)(dbase + row) * KSZ
                : x + (size_t)(bm0 + row - DCHUNK) * KSZ;
            float s = 0.f;
#pragma unroll
            for (int j = 0; j < 8; ++j) {
                float4 v = *reinterpret_cast<const float4*>(src + j * 64 + lo * 4);
                s += v.x * v.x + v.y * v.y + v.z * v.z + v.w * v.w;
            }
            s += __shfl_xor(s, 1); s += __shfl_xor(s, 2);
            s += __shfl_xor(s, 4); s += __shfl_xor(s, 8);
            if (lo == 0) {
                if (row < DCHUNK) kk_s[row] = s;
                else              xx_s[row - DCHUNK] = s;
            }
        }
    }
    __syncthreads();

    f32x4 accO[4][4];
#pragma unroll
    for (int m = 0; m < 4; ++m)
#pragma unroll
        for (int n = 0; n < 4; ++n) accO[m][n] = f32x4{0.f, 0.f, 0.f, 0.f};

    for (int it = 0; it < NITER; ++it) {
        const int d0 = dbase + it * BD;

        f32x4 accS[4][2];
#pragma unroll
        for (int m = 0; m < 4; ++m)
#pragma unroll
            for (int n = 0; n < 2; ++n) accS[m][n] = f32x4{0.f, 0.f, 0.f, 0.f};

        // ---- Phase A: accS = x_tile . keys_tile^T over K=512 ----
        for (int kc = 0; kc < NKC; ++kc) {
            __syncthreads();   // previous readers of xs/ks (or prev-iter phase B) done
            // stage xs: 128 rows x 16 float4
#pragma unroll
            for (int j = 0; j < 8; ++j) {
                const int idx = tid + j * 256;
                const int row = idx >> 4, c4 = idx & 15;
                float4 v = *reinterpret_cast<const float4*>(
                    x + (size_t)(bm0 + row) * KSZ + kc * KC + c4 * 4);
                unsigned* dst = reinterpret_cast<unsigned*>(&xs[row * XS_STRIDE + c4 * 4]);
                dst[0] = pack2(v.x, v.y); dst[1] = pack2(v.z, v.w);
            }
            // stage ks: 64 rows x 16 float4
#pragma unroll
            for (int j = 0; j < 4; ++j) {
                const int idx = tid + j * 256;
                const int row = idx >> 4, c4 = idx & 15;
                float4 v = *reinterpret_cast<const float4*>(
                    keys + (size_t)(d0 + row) * KSZ + kc * KC + c4 * 4);
                unsigned* dst = reinterpret_cast<unsigned*>(&ks[row * KS_STRIDE + c4 * 4]);
                dst[0] = pack2(v.x, v.y); dst[1] = pack2(v.z, v.w);
            }
            __syncthreads();
#pragma unroll
            for (int kst = 0; kst < 2; ++kst) {
                const int k0 = kst * 32 + hi * 8;
                short8 a[4], b[2];
#pragma unroll
                for (int m = 0; m < 4; ++m)
                    a[m] = *reinterpret_cast<const short8*>(
                        &xs[(wm * 64 + m * 16 + lo) * XS_STRIDE + k0]);
#pragma unroll
                for (int n = 0; n < 2; ++n)
                    b[n] = *reinterpret_cast<const short8*>(
                        &ks[(wn * 32 + n * 16 + lo) * KS_STRIDE + k0]);
#pragma unroll
                for (int m = 0; m < 4; ++m)
#pragma unroll
                    for (int n = 0; n < 2; ++n)
                        accS[m][n] = __builtin_amdgcn_mfma_f32_16x16x32_bf16(
                            a[m], b[n], accS[m][n], 0, 0, 0);
            }
        }

        // ---- epilogue A: kern = rcp(kk - 2S + xx + eps) -> kT (bf16) ----
#pragma unroll
        for (int m = 0; m < 4; ++m)
#pragma unroll
            for (int n = 0; n < 2; ++n) {
                const int dl = wn * 32 + n * 16 + lo;
                const float kkv = kk_s[it * BD + dl];
#pragma unroll
                for (int r = 0; r < 4; ++r) {
                    const int bl = wm * 64 + m * 16 + hi * 4 + r;
                    const float dsq = kkv + xx_s[bl] - 2.f * accS[m][n][r] + EPSV;
                    kT[bl * KT_STRIDE + dl] = f2bf(__builtin_amdgcn_rcpf(dsq));
                }
            }

        // ---- stage values tile: vls[dl][c], 64 rows x 25 float4 ----
#pragma unroll
        for (int j = 0; j < 7; ++j) {
            const int idx = tid + j * 256;
            if (idx < 1600) {
                const int row = idx / 25, c4 = idx % 25;
                float4 v = *reinterpret_cast<const float4*>(
                    values + (size_t)(d0 + row) * CC + c4 * 4);
                unsigned* dst = reinterpret_cast<unsigned*>(&vls[row * VL_STRIDE + c4 * 4]);
                dst[0] = pack2(v.x, v.y); dst[1] = pack2(v.z, v.w);
            }
        }
        __syncthreads();   // kT + vls visible

        // ---- Phase B: accO += kern(BMxBD) . values(BDxC) ----
#pragma unroll
        for (int ks2 = 0; ks2 < 2; ++ks2) {
            const int k0 = ks2 * 32 + hi * 8;
            short8 a[4], b[4];
#pragma unroll
            for (int m = 0; m < 4; ++m)
                a[m] = *reinterpret_cast<const short8*>(
                    &kT[(wm * 64 + m * 16 + lo) * KT_STRIDE + k0]);
#pragma unroll
            for (int n = 0; n < 4; ++n) {
                const int c = wn * 64 + n * 16 + lo;
                short8 t = {0, 0, 0, 0, 0, 0, 0, 0};
                if (c < CC) {
#pragma unroll
                    for (int i = 0; i < 8; ++i)
                        t[i] = (short)vls[(k0 + i) * VL_STRIDE + c];
                }
                b[n] = t;
            }
#pragma unroll
            for (int m = 0; m < 4; ++m)
#pragma unroll
                for (int n = 0; n < 4; ++n)
                    accO[m][n] = __builtin_amdgcn_mfma_f32_16x16x32_bf16(
                        a[m], b[n], accO[m][n], 0, 0, 0);
        }
    }

    // ---- write out: atomic accumulate across D-chunks ----
#pragma unroll
    for (int m = 0; m < 4; ++m)
#pragma unroll
        for (int n = 0; n < 4; ++n) {
            const int c = wn * 64 + n * 16 + lo;
            if (c < CC) {
#pragma unroll
                for (int r = 0; r < 4; ++r) {
                    const int b_ = bm0 + wm * 64 + m * 16 + hi * 4 + r;
                    atomicAdd(&out[(size_t)b_ * CC + c], accO[m][n][r]);
                }
            }
        }
}

extern "C" void kernel_launch(void* const* d_in, const int* in_sizes, int n_in,
                              void* d_out, int out_size, void* d_ws, size_t ws_size,
                              hipStream_t stream) {
    const float* x      = (const float*)d_in[0];
    const float* keys   = (const float*)d_in[1];
    const float* values = (const float*)d_in[2];
    float* out = (float*)d_out;

    hipMemsetAsync(d_out, 0, (size_t)out_size * sizeof(float), stream);

    const size_t ws_need = (size_t)(DSZ + BSZ) * sizeof(float);  // 80 KB
    const int use_ws = (ws_size >= ws_need) ? 1 : 0;
    float* kk = (float*)d_ws;
    float* xx = kk + DSZ;
    if (use_ws) {
        varkeys_pre<<<dim3((DSZ + BSZ) / 16), dim3(256), 0, stream>>>(x, keys, kk, xx);
    }
    varkeys_main<<<dim3(BSZ / BM, DSPLIT), dim3(256), 0, stream>>>(
        x, keys, values, out, kk, xx, use_ws);
}

// Round 2
// 208.745 us; speedup vs baseline: 2.3490x; 2.3490x over previous
//
#include <hip/hip_runtime.h>
#include <hip/hip_bf16.h>
#include <cstdint>

// Varkeys: out[b,c] = sum_d values[d,c] / (||k_d||^2 - 2 k_d.x_b + ||x_b||^2 + EPS)
// Fast path: pre-convert inputs to bf16 (swizzled) in ws, then fused MFMA kernel
// with global_load_lds staging, dbuf'd keys tiles, counted vmcnt, raw barriers.
// B=4096 D=16384 K=512 C=100 (padded 128).

#define BSZ   4096
#define DSZ   16384
#define KSZ   512
#define CC    100
#define CP    128
#define EPSV  1e-4f

#define BM     128
#define BD     64
#define DSPLIT 16
#define DCHUNK (DSZ / DSPLIT)   // 1024
#define NITER  (DCHUNK / BD)    // 16
#define KC     64
#define NKC    (KSZ / KC)       // 8

typedef short  short8 __attribute__((ext_vector_type(8)));
typedef float  f32x4  __attribute__((ext_vector_type(4)));
typedef unsigned int   u32;
typedef unsigned short u16;

__device__ __forceinline__ u16 f2bf(float f) {
    union { float f; u32 u; } cv; cv.f = f;
    u32 u = cv.u;
    u += 0x7fffu + ((u >> 16) & 1u);   // RNE
    return (u16)(u >> 16);
}
__device__ __forceinline__ u32 pack2(float a, float b) {
    return (u32)f2bf(a) | ((u32)f2bf(b) << 16);
}

__device__ __forceinline__ void gload_lds16(const void* g, void* l) {
    __builtin_amdgcn_global_load_lds(
        (const __attribute__((address_space(1))) u32*)g,
        (__attribute__((address_space(3))) u32*)l, 16, 0, 0);
}

// ---------------- fast-path pre-kernels ----------------

// x,keys -> bf16, swizzled within 64-col chunks by (row&7)<<3; fused row norms.
__global__ __launch_bounds__(256)
void convert_xk(const float* __restrict__ x, const float* __restrict__ keys,
                u16* __restrict__ xw, u16* __restrict__ kw,
                float* __restrict__ kk, float* __restrict__ xx)
{
    const int tid = threadIdx.x, wid = tid >> 6, lane = tid & 63;
    const int row = blockIdx.x * 4 + wid;           // 0..20479
    const float* src; u16* dst; float* nrm; int r;
    if (row < DSZ) { r = row;       src = keys + (size_t)r * KSZ; dst = kw + (size_t)r * KSZ; nrm = kk + r; }
    else           { r = row - DSZ; src = x    + (size_t)r * KSZ; dst = xw + (size_t)r * KSZ; nrm = xx + r; }

    float4 v0 = *reinterpret_cast<const float4*>(src + lane * 8);
    float4 v1 = *reinterpret_cast<const float4*>(src + lane * 8 + 4);
    float s = v0.x*v0.x + v0.y*v0.y + v0.z*v0.z + v0.w*v0.w
            + v1.x*v1.x + v1.y*v1.y + v1.z*v1.z + v1.w*v1.w;

    uint4 w;
    w.x = pack2(v0.x, v0.y); w.y = pack2(v0.z, v0.w);
    w.z = pack2(v1.x, v1.y); w.w = pack2(v1.z, v1.w);
    const int dcol = ((lane >> 3) << 6) + (((lane & 7) ^ (r & 7)) << 3);
    *reinterpret_cast<uint4*>(dst + dcol) = w;

    s += __shfl_xor(s, 1);  s += __shfl_xor(s, 2);  s += __shfl_xor(s, 4);
    s += __shfl_xor(s, 8);  s += __shfl_xor(s, 16); s += __shfl_xor(s, 32);
    if (lane == 0) *nrm = s;
}

// values [D][100] f32 -> vw [128][D] bf16 (transposed, c>=100 zero),
// swizzled within 64-d chunks by (c&7)<<3.
__global__ __launch_bounds__(256)
void convert_v(const float* __restrict__ values, u16* __restrict__ vw)
{
    const int gid = blockIdx.x * 256 + threadIdx.x;   // 0..262143
    const int c = gid >> 11;                          // 0..127
    const int j = gid & 2047;                         // d-group of 8
    const int dp  = ((j >> 3) << 6) + ((j & 7) << 3);
    const int dsg = ((j >> 3) << 6) + (((j & 7) ^ (c & 7)) << 3);
    uint4 w = make_uint4(0, 0, 0, 0);
    if (c < CC) {
        float f[8];
#pragma unroll
        for (int i = 0; i < 8; ++i) f[i] = values[(size_t)(dsg + i) * CC + c];
        w.x = pack2(f[0], f[1]); w.y = pack2(f[2], f[3]);
        w.z = pack2(f[4], f[5]); w.w = pack2(f[6], f[7]);
    }
    *reinterpret_cast<uint4*>(vw + (size_t)c * DSZ + dp) = w;
}

// ---------------- fast main kernel ----------------
__global__ __launch_bounds__(256, 2)
void varkeys_fast(const u16* __restrict__ xw, const u16* __restrict__ kw,
                  const u16* __restrict__ vw, const float* __restrict__ kkp,
                  const float* __restrict__ xxp, float* __restrict__ out)
{
    __shared__ __align__(16) u16 xs[BM * KC];        // 16KB x tile
    __shared__ __align__(16) u16 ksb[2][BD * KC];    // 16KB keys dbuf
    __shared__ __align__(16) u16 kT[BM * BD];        // 16KB kern tile
    __shared__ __align__(16) u16 vT[CP * BD];        // 16KB values^T tile
    __shared__ float kk_s[DCHUNK];
    __shared__ float xx_s[BM];

    const int tid  = threadIdx.x;
    const int wid  = tid >> 6;
    const int lane = tid & 63;
    const int lo   = lane & 15;
    const int hi   = lane >> 4;
    const int wm   = wid >> 1;
    const int wn   = wid & 1;

    // XCD-aware swizzle: each XCD serves 2 contiguous dict chunks.
    const int h    = blockIdx.x;
    const int xcd  = h & 7, slot = h >> 3;
    const int by   = xcd * 2 + (slot >> 5);
    const int bx   = slot & 31;
    const int bm0   = bx * BM;
    const int dbase = by * DCHUNK;

    for (int i = tid; i < DCHUNK; i += 256) kk_s[i] = kkp[dbase + i];
    if (tid < BM) xx_s[tid] = xxp[bm0 + tid];

    f32x4 accO[4][4];
#pragma unroll
    for (int m = 0; m < 4; ++m)
#pragma unroll
        for (int n = 0; n < 4; ++n) accO[m][n] = f32x4{0.f, 0.f, 0.f, 0.f};

    __syncthreads();

    // prefetch ks(it=0, kc=0) -> buf 0
#pragma unroll
    for (int i = 0; i < 2; ++i) {
        const int inst = wid * 2 + i;
        const int flat = inst * 512 + lane * 8;
        gload_lds16(kw + (size_t)(dbase + (flat >> 6)) * KSZ + (flat & 63),
                    (char*)ksb[0] + inst * 1024);
    }
    int cur = 0;

    for (int it = 0; it < NITER; ++it) {
        const int d0 = dbase + it * BD;

        f32x4 accS[4][2];
#pragma unroll
        for (int m = 0; m < 4; ++m)
#pragma unroll
            for (int n = 0; n < 2; ++n) accS[m][n] = f32x4{0.f, 0.f, 0.f, 0.f};

        for (int kc = 0; kc < NKC; ++kc) {
            __builtin_amdgcn_s_barrier();   // overwrite-protect (no vm drain)

            // stage xs(kc): 16KB, 4 insts/wave
#pragma unroll
            for (int i = 0; i < 4; ++i) {
                const int inst = wid * 4 + i;
                const int flat = inst * 512 + lane * 8;
                gload_lds16(xw + (size_t)(bm0 + (flat >> 6)) * KSZ + kc * KC + (flat & 63),
                            (char*)xs + inst * 1024);
            }
            if (kc == 0) {                  // stage vT(it): 16KB, hidden under phase A
#pragma unroll
                for (int i = 0; i < 4; ++i) {
                    const int inst = wid * 4 + i;
                    const int flat = inst * 512 + lane * 8;
                    gload_lds16(vw + (size_t)(flat >> 6) * DSZ + d0 + (flat & 63),
                                (char*)vT + inst * 1024);
                }
            }
            const bool pf = !(it == NITER - 1 && kc == NKC - 1);
            if (pf) {                       // prefetch next ks tile (stays in flight)
                const int nd0 = (kc < NKC - 1) ? d0 : d0 + BD;
                const int nkc = (kc < NKC - 1) ? kc + 1 : 0;
#pragma unroll
                for (int i = 0; i < 2; ++i) {
                    const int inst = wid * 2 + i;
                    const int flat = inst * 512 + lane * 8;
                    gload_lds16(kw + (size_t)(nd0 + (flat >> 6)) * KSZ + nkc * KC + (flat & 63),
                                (char*)ksb[cur ^ 1] + inst * 1024);
                }
                asm volatile("s_waitcnt vmcnt(2)" ::: "memory");
            } else {
                asm volatile("s_waitcnt vmcnt(0)" ::: "memory");
            }
            __builtin_amdgcn_s_barrier();   // publish
            __builtin_amdgcn_sched_barrier(0);

            const u16* ksc = ksb[cur];
            const int swz = (lo & 7) << 3;
#pragma unroll
            for (int kst = 0; kst < 2; ++kst) {
                const int k0 = (kst * 32 + hi * 8) ^ swz;
                short8 a[4], b[2];
#pragma unroll
                for (int m = 0; m < 4; ++m)
                    a[m] = *reinterpret_cast<const short8*>(&xs[(wm * 64 + m * 16 + lo) * KC + k0]);
#pragma unroll
                for (int n = 0; n < 2; ++n)
                    b[n] = *reinterpret_cast<const short8*>(&ksc[(wn * 32 + n * 16 + lo) * KC + k0]);
#pragma unroll
                for (int m = 0; m < 4; ++m)
#pragma unroll
                    for (int n = 0; n < 2; ++n)
                        accS[m][n] = __builtin_amdgcn_mfma_f32_16x16x32_bf16(
                            a[m], b[n], accS[m][n], 0, 0, 0);
            }
            cur ^= 1;
        }

        // epilogue A: kern = rcp(kk - 2S + xx + eps) -> kT (swizzled)
#pragma unroll
        for (int m = 0; m < 4; ++m)
#pragma unroll
            for (int n = 0; n < 2; ++n) {
                const int dl = wn * 32 + n * 16 + lo;
                const float kkv = kk_s[it * BD + dl];
#pragma unroll
                for (int r = 0; r < 4; ++r) {
                    const int bl = wm * 64 + m * 16 + hi * 4 + r;
                    const float dsq = kkv + xx_s[bl] - 2.f * accS[m][n][r] + EPSV;
                    kT[bl * BD + (dl ^ ((bl & 7) << 3))] = f2bf(__builtin_amdgcn_rcpf(dsq));
                }
            }
        asm volatile("s_waitcnt lgkmcnt(0)" ::: "memory");
        __builtin_amdgcn_s_barrier();       // publish kT (keeps ks prefetch in flight)
        __builtin_amdgcn_sched_barrier(0);

        // phase B: accO += kern(128x64) . V^T rows (128 c-rows x 64 d)
        {
            const int swz = (lo & 7) << 3;
#pragma unroll
            for (int ks2 = 0; ks2 < 2; ++ks2) {
                const int k0 = (ks2 * 32 + hi * 8) ^ swz;
                short8 a[4], b[4];
#pragma unroll
                for (int m = 0; m < 4; ++m)
                    a[m] = *reinterpret_cast<const short8*>(&kT[(wm * 64 + m * 16 + lo) * BD + k0]);
#pragma unroll
                for (int n = 0; n < 4; ++n)
                    b[n] = *reinterpret_cast<const short8*>(&vT[(wn * 64 + n * 16 + lo) * BD + k0]);
#pragma unroll
                for (int m = 0; m < 4; ++m)
#pragma unroll
                    for (int n = 0; n < 4; ++n)
                        accO[m][n] = __builtin_amdgcn_mfma_f32_16x16x32_bf16(
                            a[m], b[n], accO[m][n], 0, 0, 0);
            }
        }
    }

    // out: atomic accumulate across D-chunks
#pragma unroll
    for (int m = 0; m < 4; ++m)
#pragma unroll
        for (int n = 0; n < 4; ++n) {
            const int c = wn * 64 + n * 16 + lo;
            if (c < CC) {
#pragma unroll
                for (int r = 0; r < 4; ++r) {
                    const int b_ = bm0 + wm * 64 + m * 16 + hi * 4 + r;
                    atomicAdd(&out[(size_t)b_ * CC + c], accO[m][n][r]);
                }
            }
        }
}

// ---------------- slow fallback (round-1, passed) ----------------

#define XS_STRIDE 72
#define KS_STRIDE 72
#define KT_STRIDE 72
#define VL_STRIDE 106

__global__ __launch_bounds__(256)
void varkeys_pre(const float* __restrict__ x, const float* __restrict__ keys,
                 float* __restrict__ kk, float* __restrict__ xx)
{
    const int tid  = threadIdx.x;
    const int wid  = tid >> 6;
    const int lane = tid & 63;
    const int lo   = lane & 15;
    const int sub  = lane >> 4;
    const int row  = blockIdx.x * 16 + wid * 4 + sub;
    const float* src = (row < DSZ) ? keys + (size_t)row * KSZ
                                   : x + (size_t)(row - DSZ) * KSZ;
    float s = 0.f;
#pragma unroll
    for (int j = 0; j < 8; ++j) {
        float4 v = *reinterpret_cast<const float4*>(src + j * 64 + lo * 4);
        s += v.x * v.x + v.y * v.y + v.z * v.z + v.w * v.w;
    }
    s += __shfl_xor(s, 1); s += __shfl_xor(s, 2);
    s += __shfl_xor(s, 4); s += __shfl_xor(s, 8);
    if (lo == 0) {
        if (row < DSZ) kk[row] = s;
        else           xx[row - DSZ] = s;
    }
}

__global__ __launch_bounds__(256, 2)
void varkeys_main(const float* __restrict__ x, const float* __restrict__ keys,
                  const float* __restrict__ values, float* __restrict__ out,
                  const float* __restrict__ kk_ws, const float* __restrict__ xx_ws,
                  int use_ws)
{
    __shared__ __align__(16) u16 xs[BM * XS_STRIDE];
    __shared__ __align__(16) u16 ks[BD * KS_STRIDE];
    __shared__ __align__(16) u16 kT[BM * KT_STRIDE];
    __shared__ __align__(16) u16 vls[BD * VL_STRIDE];
    __shared__ float kk_s[DCHUNK];
    __shared__ float xx_s[BM];

    const int tid  = threadIdx.x;
    const int wid  = tid >> 6;
    const int lane = tid & 63;
    const int lo   = lane & 15;
    const int hi   = lane >> 4;
    const int wm   = wid >> 1;
    const int wn   = wid & 1;
    const int bm0   = blockIdx.x * BM;
    const int dbase = blockIdx.y * DCHUNK;

    if (use_ws) {
        for (int i = tid; i < DCHUNK; i += 256) kk_s[i] = kk_ws[dbase + i];
        if (tid < BM) xx_s[tid] = xx_ws[bm0 + tid];
    } else {
        for (int rbase = wid * 4; rbase < DCHUNK + BM; rbase += 16) {
            const int row = rbase + hi;
            const float* src = (row < DCHUNK)
                ? keys + (size_t)(dbase + row) * KSZ
                : x + (size_t)(bm0 + row - DCHUNK) * KSZ;
            float s = 0.f;
#pragma unroll
            for (int j = 0; j < 8; ++j) {
                float4 v = *reinterpret_cast<const float4*>(src + j * 64 + lo * 4);
                s += v.x * v.x + v.y * v.y + v.z * v.z + v.w * v.w;
            }
            s += __shfl_xor(s, 1); s += __shfl_xor(s, 2);
            s += __shfl_xor(s, 4); s += __shfl_xor(s, 8);
            if (lo == 0) {
                if (row < DCHUNK) kk_s[row] = s;
                else              xx_s[row - DCHUNK] = s;
            }
        }
    }
    __syncthreads();

    f32x4 accO[4][4];
#pragma unroll
    for (int m = 0; m < 4; ++m)
#pragma unroll
        for (int n = 0; n < 4; ++n) accO[m][n] = f32x4{0.f, 0.f, 0.f, 0.f};

    for (int it = 0; it < NITER; ++it) {
        const int d0 = dbase + it * BD;

        f32x4 accS[4][2];
#pragma unroll
        for (int m = 0; m < 4; ++m)
#pragma unroll
            for (int n = 0; n < 2; ++n) accS[m][n] = f32x4{0.f, 0.f, 0.f, 0.f};

        for (int kc = 0; kc < NKC; ++kc) {
            __syncthreads();
#pragma unroll
            for (int j = 0; j < 8; ++j) {
                const int idx = tid + j * 256;
                const int row = idx >> 4, c4 = idx & 15;
                float4 v = *reinterpret_cast<const float4*>(
                    x + (size_t)(bm0 + row) * KSZ + kc * KC + c4 * 4);
                u32* dst = reinterpret_cast<u32*>(&xs[row * XS_STRIDE + c4 * 4]);
                dst[0] = pack2(v.x, v.y); dst[1] = pack2(v.z, v.w);
            }
#pragma unroll
            for (int j = 0; j < 4; ++j) {
                const int idx = tid + j * 256;
                const int row = idx >> 4, c4 = idx & 15;
                float4 v = *reinterpret_cast<const float4*>(
                    keys + (size_t)(d0 + row) * KSZ + kc * KC + c4 * 4);
                u32* dst = reinterpret_cast<u32*>(&ks[row * KS_STRIDE + c4 * 4]);
                dst[0] = pack2(v.x, v.y); dst[1] = pack2(v.z, v.w);
            }
            __syncthreads();
#pragma unroll
            for (int kst = 0; kst < 2; ++kst) {
                const int k0 = kst * 32 + hi * 8;
                short8 a[4], b[2];
#pragma unroll
                for (int m = 0; m < 4; ++m)
                    a[m] = *reinterpret_cast<const short8*>(
                        &xs[(wm * 64 + m * 16 + lo) * XS_STRIDE + k0]);
#pragma unroll
                for (int n = 0; n < 2; ++n)
                    b[n] = *reinterpret_cast<const short8*>(
                        &ks[(wn * 32 + n * 16 + lo) * KS_STRIDE + k0]);
#pragma unroll
                for (int m = 0; m < 4; ++m)
#pragma unroll
                    for (int n = 0; n < 2; ++n)
                        accS[m][n] = __builtin_amdgcn_mfma_f32_16x16x32_bf16(
                            a[m], b[n], accS[m][n], 0, 0, 0);
            }
        }

#pragma unroll
        for (int m = 0; m < 4; ++m)
#pragma unroll
            for (int n = 0; n < 2; ++n) {
                const int dl = wn * 32 + n * 16 + lo;
                const float kkv = kk_s[it * BD + dl];
#pragma unroll
                for (int r = 0; r < 4; ++r) {
                    const int bl = wm * 64 + m * 16 + hi * 4 + r;
                    const float dsq = kkv + xx_s[bl] - 2.f * accS[m][n][r] + EPSV;
                    kT[bl * KT_STRIDE + dl] = f2bf(__builtin_amdgcn_rcpf(dsq));
                }
            }

#pragma unroll
        for (int j = 0; j < 7; ++j) {
            const int idx = tid + j * 256;
            if (idx < 1600) {
                const int row = idx / 25, c4 = idx % 25;
                float4 v = *reinterpret_cast<const float4*>(
                    values + (size_t)(d0 + row) * CC + c4 * 4);
                u32* dst = reinterpret_cast<u32*>(&vls[row * VL_STRIDE + c4 * 4]);
                dst[0] = pack2(v.x, v.y); dst[1] = pack2(v.z, v.w);
            }
        }
        __syncthreads();

#pragma unroll
        for (int ks2 = 0; ks2 < 2; ++ks2) {
            const int k0 = ks2 * 32 + hi * 8;
            short8 a[4], b[4];
#pragma unroll
            for (int m = 0; m < 4; ++m)
                a[m] = *reinterpret_cast<const short8*>(
                    &kT[(wm * 64 + m * 16 + lo) * KT_STRIDE + k0]);
#pragma unroll
            for (int n = 0; n < 4; ++n) {
                const int c = wn * 64 + n * 16 + lo;
                short8 t = {0, 0, 0, 0, 0, 0, 0, 0};
                if (c < CC) {
#pragma unroll
                    for (int i = 0; i < 8; ++i)
                        t[i] = (short)vls[(k0 + i) * VL_STRIDE + c];
                }
                b[n] = t;
            }
#pragma unroll
            for (int m = 0; m < 4; ++m)
#pragma unroll
                for (int n = 0; n < 4; ++n)
                    accO[m][n] = __builtin_amdgcn_mfma_f32_16x16x32_bf16(
                        a[m], b[n], accO[m][n], 0, 0, 0);
        }
    }

#pragma unroll
    for (int m = 0; m < 4; ++m)
#pragma unroll
        for (int n = 0; n < 4; ++n) {
            const int c = wn * 64 + n * 16 + lo;
            if (c < CC) {
#pragma unroll
                for (int r = 0; r < 4; ++r) {
                    const int b_ = bm0 + wm * 64 + m * 16 + hi * 4 + r;
                    atomicAdd(&out[(size_t)b_ * CC + c], accO[m][n][r]);
                }
            }
        }
}

extern "C" void kernel_launch(void* const* d_in, const int* in_sizes, int n_in,
                              void* d_out, int out_size, void* d_ws, size_t ws_size,
                              hipStream_t stream) {
    const float* x      = (const float*)d_in[0];
    const float* keys   = (const float*)d_in[1];
    const float* values = (const float*)d_in[2];
    float* out = (float*)d_out;

    hipMemsetAsync(d_out, 0, (size_t)out_size * sizeof(float), stream);

    // fast-path ws layout
    const size_t off_xw = 0;
    const size_t off_kw = off_xw + (size_t)BSZ * KSZ * 2;   //  4 MB
    const size_t off_vw = off_kw + (size_t)DSZ * KSZ * 2;   // +16 MB
    const size_t off_kk = off_vw + (size_t)CP * DSZ * 2;    //  +4 MB
    const size_t off_xx = off_kk + (size_t)DSZ * 4;
    const size_t need   = off_xx + (size_t)BSZ * 4;         // ~24.1 MB

    if (ws_size >= need) {
        u16* xw = (u16*)((char*)d_ws + off_xw);
        u16* kw = (u16*)((char*)d_ws + off_kw);
        u16* vw = (u16*)((char*)d_ws + off_vw);
        float* kk = (float*)((char*)d_ws + off_kk);
        float* xx = (float*)((char*)d_ws + off_xx);
        convert_xk<<<dim3((DSZ + BSZ) / 4), dim3(256), 0, stream>>>(x, keys, xw, kw, kk, xx);
        convert_v<<<dim3((CP * DSZ / 8) / 256), dim3(256), 0, stream>>>(values, vw);
        varkeys_fast<<<dim3(DSPLIT * (BSZ / BM)), dim3(256), 0, stream>>>(xw, kw, vw, kk, xx, out);
    } else {
        const size_t ws_need = (size_t)(DSZ + BSZ) * sizeof(float);  // 80 KB
        const int use_ws = (ws_size >= ws_need) ? 1 : 0;
        float* kk = (float*)d_ws;
        float* xx = kk + DSZ;
        if (use_ws) {
            varkeys_pre<<<dim3((DSZ + BSZ) / 16), dim3(256), 0, stream>>>(x, keys, kk, xx);
        }
        varkeys_main<<<dim3(BSZ / BM, DSPLIT), dim3(256), 0, stream>>>(
            x, keys, values, out, kk, xx, use_ws);
    }
}

// Round 3
// 136.337 us; speedup vs baseline: 3.5965x; 1.5311x over previous
//
#include <hip/hip_runtime.h>
#include <hip/hip_bf16.h>
#include <cstdint>

// Varkeys: out[b,c] = sum_d values[d,c] / (||k_d||^2 - 2 k_d.x_b + ||x_b||^2 + EPS)
// R3: x fragments register-resident (loaded once), keys KC=256 dbuf pipeline with
// counted vmcnt, vT/kk prefetched at it-start, 512 threads, grid = 256 WGs (1/CU).
// B=4096 D=16384 K=512 C=100 (padded 128). bf16 MFMA 16x16x32, fp32 accum.

#define BSZ   4096
#define DSZ   16384
#define KSZ   512
#define CC    100
#define CP    128
#define EPSV  1e-4f

#define BM     128
#define BD     64
#define DSPLIT 8
#define DCHUNK (DSZ / DSPLIT)   // 2048
#define NITER  (DCHUNK / BD)    // 32
#define KC     256              // keys chunk cols; 2 chunks per it

typedef short  short8 __attribute__((ext_vector_type(8)));
typedef float  f32x4  __attribute__((ext_vector_type(4)));
typedef unsigned int   u32;
typedef unsigned short u16;

__device__ __forceinline__ u16 f2bf(float f) {
    union { float f; u32 u; } cv; cv.f = f;
    u32 u = cv.u;
    u += 0x7fffu + ((u >> 16) & 1u);   // RNE
    return (u16)(u >> 16);
}
__device__ __forceinline__ u32 pack2(float a, float b) {
    return (u32)f2bf(a) | ((u32)f2bf(b) << 16);
}

__device__ __forceinline__ void gload_lds16(const void* g, void* l) {
    __builtin_amdgcn_global_load_lds(
        (const __attribute__((address_space(1))) u32*)g,
        (__attribute__((address_space(3))) u32*)l, 16, 0, 0);
}

// ---------------- fast-path pre-kernels ----------------

// x,keys -> bf16, swizzled within 64-col chunks by (row&7)<<3; fused row norms.
__global__ __launch_bounds__(256)
void convert_xk(const float* __restrict__ x, const float* __restrict__ keys,
                u16* __restrict__ xw, u16* __restrict__ kw,
                float* __restrict__ kk, float* __restrict__ xx)
{
    const int tid = threadIdx.x, wid = tid >> 6, lane = tid & 63;
    const int row = blockIdx.x * 4 + wid;           // 0..20479
    const float* src; u16* dst; float* nrm; int r;
    if (row < DSZ) { r = row;       src = keys + (size_t)r * KSZ; dst = kw + (size_t)r * KSZ; nrm = kk + r; }
    else           { r = row - DSZ; src = x    + (size_t)r * KSZ; dst = xw + (size_t)r * KSZ; nrm = xx + r; }

    float4 v0 = *reinterpret_cast<const float4*>(src + lane * 8);
    float4 v1 = *reinterpret_cast<const float4*>(src + lane * 8 + 4);
    float s = v0.x*v0.x + v0.y*v0.y + v0.z*v0.z + v0.w*v0.w
            + v1.x*v1.x + v1.y*v1.y + v1.z*v1.z + v1.w*v1.w;

    uint4 w;
    w.x = pack2(v0.x, v0.y); w.y = pack2(v0.z, v0.w);
    w.z = pack2(v1.x, v1.y); w.w = pack2(v1.z, v1.w);
    const int dcol = ((lane >> 3) << 6) + (((lane & 7) ^ (r & 7)) << 3);
    *reinterpret_cast<uint4*>(dst + dcol) = w;

    s += __shfl_xor(s, 1);  s += __shfl_xor(s, 2);  s += __shfl_xor(s, 4);
    s += __shfl_xor(s, 8);  s += __shfl_xor(s, 16); s += __shfl_xor(s, 32);
    if (lane == 0) *nrm = s;
}

// values [D][100] f32 -> vw [128][D] bf16 (transposed, c>=100 zero),
// swizzled within 64-d chunks by (c&7)<<3.
__global__ __launch_bounds__(256)
void convert_v(const float* __restrict__ values, u16* __restrict__ vw)
{
    const int gid = blockIdx.x * 256 + threadIdx.x;   // 0..262143
    const int c = gid >> 11;                          // 0..127
    const int j = gid & 2047;                         // d-group of 8
    const int dp  = ((j >> 3) << 6) + ((j & 7) << 3);
    const int dsg = ((j >> 3) << 6) + (((j & 7) ^ (c & 7)) << 3);
    uint4 w = make_uint4(0, 0, 0, 0);
    if (c < CC) {
        float f[8];
#pragma unroll
        for (int i = 0; i < 8; ++i) f[i] = values[(size_t)(dsg + i) * CC + c];
        w.x = pack2(f[0], f[1]); w.y = pack2(f[2], f[3]);
        w.z = pack2(f[4], f[5]); w.w = pack2(f[6], f[7]);
    }
    *reinterpret_cast<uint4*>(vw + (size_t)c * DSZ + dp) = w;
}

// ---------------- fast main kernel: 512 threads, x in registers ----------------
__global__ __launch_bounds__(512, 2)
void varkeys_fast(const u16* __restrict__ xw, const u16* __restrict__ kw,
                  const u16* __restrict__ vw, const float* __restrict__ kkp,
                  const float* __restrict__ xxp, float* __restrict__ out)
{
    __shared__ __align__(16) u16 ksb0[BD * KC];     // 32KB keys chunk buf 0
    __shared__ __align__(16) u16 ksb1[BD * KC];     // 32KB keys chunk buf 1
    __shared__ __align__(16) u16 kT[BM * BD];       // 16KB kern tile
    __shared__ __align__(16) u16 vT[CP * BD];       // 16KB values^T tile
    __shared__ float xx_s[BM];

    const int tid  = threadIdx.x;
    const int wid  = tid >> 6;     // 0..7
    const int lane = tid & 63;
    const int lo   = lane & 15;
    const int hi   = lane >> 4;
    const int wm   = wid >> 1;     // 0..3 : rows wm*32..+31
    const int wn   = wid & 1;      // phase A: dict half wn*32; phase B: col half wn*64

    // dchunk pinned per XCD (bid%8 == XCD id); 32 b-blocks per dchunk.
    const int h  = blockIdx.x;
    const int by = h & 7, bx = h >> 3;
    const int bm0   = bx * BM;
    const int dbase = by * DCHUNK;

    if (tid < BM) xx_s[tid] = xxp[bm0 + tid];

    // ---- x fragments: 2 m-frags x 16 k-slices, register resident ----
    short8 xf[2][16];
    {
        const int rbase = bm0 + wm * 32 + lo;
#pragma unroll
        for (int m = 0; m < 2; ++m) {
            const int row = rbase + m * 16;
            const size_t roff = (size_t)row * KSZ;
            const int rs = (row & 7) << 3;
#pragma unroll
            for (int t = 0; t < 16; ++t) {
                const int col = (t * 32 + hi * 8) ^ rs;
                xf[m][t] = *reinterpret_cast<const short8*>(xw + roff + col);
            }
        }
    }

    f32x4 accO[2][4];
#pragma unroll
    for (int m = 0; m < 2; ++m)
#pragma unroll
        for (int n = 0; n < 4; ++n) accO[m][n] = f32x4{0.f, 0.f, 0.f, 0.f};

    // prologue: issue ks(it0, chunk0) -> ksb0
#pragma unroll
    for (int i = 0; i < 4; ++i) {
        const int ci = wid * 4 + i, flat = ci * 512 + lane * 8;
        gload_lds16(kw + (size_t)(dbase + (flat >> 8)) * KSZ + (flat & 255),
                    (char*)ksb0 + ci * 1024);
    }
    asm volatile("s_waitcnt lgkmcnt(0)" ::: "memory");   // xx_s visible
    __builtin_amdgcn_s_barrier();

    const int swz = (lo & 7) << 3;

#define PHASE_A(CHUNK, KSBUF)                                                        \
    {                                                                                \
        _Pragma("unroll")                                                            \
        for (int j = 0; j < 8; ++j) {                                                \
            const int k0 = (j * 32 + hi * 8) ^ swz;                                  \
            short8 b0 = *reinterpret_cast<const short8*>(&KSBUF[(wn*32 + lo)*KC + k0]);      \
            short8 b1 = *reinterpret_cast<const short8*>(&KSBUF[(wn*32 + 16 + lo)*KC + k0]); \
            accS[0][0] = __builtin_amdgcn_mfma_f32_16x16x32_bf16(xf[0][(CHUNK)*8+j], b0, accS[0][0], 0,0,0); \
            accS[1][0] = __builtin_amdgcn_mfma_f32_16x16x32_bf16(xf[1][(CHUNK)*8+j], b0, accS[1][0], 0,0,0); \
            accS[0][1] = __builtin_amdgcn_mfma_f32_16x16x32_bf16(xf[0][(CHUNK)*8+j], b1, accS[0][1], 0,0,0); \
            accS[1][1] = __builtin_amdgcn_mfma_f32_16x16x32_bf16(xf[1][(CHUNK)*8+j], b1, accS[1][1], 0,0,0); \
        }                                                                            \
    }

    for (int it = 0; it < NITER; ++it) {
        const int d0 = dbase + it * BD;

        f32x4 accS[2][2];
#pragma unroll
        for (int m = 0; m < 2; ++m)
#pragma unroll
            for (int n = 0; n < 2; ++n) accS[m][n] = f32x4{0.f, 0.f, 0.f, 0.f};

        // ======== even step: compute chunk0 from ksb0 ========
        __builtin_amdgcn_s_barrier();            // protect ksb1 + vT overwrite
        // issue ks(it, chunk1) -> ksb1
#pragma unroll
        for (int i = 0; i < 4; ++i) {
            const int ci = wid * 4 + i, flat = ci * 512 + lane * 8;
            gload_lds16(kw + (size_t)(d0 + (flat >> 8)) * KSZ + KC + (flat & 255),
                        (char*)ksb1 + ci * 1024);
        }
        // issue vT(it)
#pragma unroll
        for (int i = 0; i < 2; ++i) {
            const int ci = wid * 2 + i, flat = ci * 512 + lane * 8;
            gload_lds16(vw + (size_t)(flat >> 6) * DSZ + d0 + (flat & 63),
                        (char*)vT + ci * 1024);
        }
        // kk(it) -> regs (2 VMEM loads, counted in vmcnt)
        const float kkf0 = kkp[d0 + wn * 32 + lo];
        const float kkf1 = kkp[d0 + wn * 32 + 16 + lo];
        asm volatile("s_waitcnt vmcnt(8)" ::: "memory");   // ks(it,chunk0) done
        __builtin_amdgcn_s_barrier();
        __builtin_amdgcn_sched_barrier(0);
        PHASE_A(0, ksb0)

        // ======== odd step: compute chunk1 from ksb1 ========
        __builtin_amdgcn_s_barrier();            // protect ksb0 overwrite
        if (it < NITER - 1) {
            const int nd0 = d0 + BD;
#pragma unroll
            for (int i = 0; i < 4; ++i) {
                const int ci = wid * 4 + i, flat = ci * 512 + lane * 8;
                gload_lds16(kw + (size_t)(nd0 + (flat >> 8)) * KSZ + (flat & 255),
                            (char*)ksb0 + ci * 1024);
            }
            asm volatile("s_waitcnt vmcnt(4)" ::: "memory");  // ks(it,ch1)+vT+kk done
        } else {
            asm volatile("s_waitcnt vmcnt(0)" ::: "memory");
        }
        __builtin_amdgcn_s_barrier();
        __builtin_amdgcn_sched_barrier(0);
        PHASE_A(1, ksb1)

        // ---- epilogue A: kern = rcp(kk - 2S + xx + eps) -> kT (swizzled) ----
#pragma unroll
        for (int m = 0; m < 2; ++m)
#pragma unroll
            for (int n = 0; n < 2; ++n) {
                const int dl = wn * 32 + n * 16 + lo;
                const float kkv = n ? kkf1 : kkf0;
#pragma unroll
                for (int r = 0; r < 4; ++r) {
                    const int rowl = wm * 32 + m * 16 + hi * 4 + r;
                    const float dsq = kkv + xx_s[rowl] - 2.f * accS[m][n][r] + EPSV;
                    kT[rowl * BD + (dl ^ ((rowl & 7) << 3))] = f2bf(__builtin_amdgcn_rcpf(dsq));
                }
            }
        asm volatile("s_waitcnt lgkmcnt(0)" ::: "memory");
        __builtin_amdgcn_s_barrier();            // publish kT (prefetch stays in flight)
        __builtin_amdgcn_sched_barrier(0);

        // ---- phase B: accO += kern(128x64) . V^T ----
#pragma unroll
        for (int kst = 0; kst < 2; ++kst) {
            const int k0 = (kst * 32 + hi * 8) ^ swz;
            short8 a0 = *reinterpret_cast<const short8*>(&kT[(wm * 32 + lo) * BD + k0]);
            short8 a1 = *reinterpret_cast<const short8*>(&kT[(wm * 32 + 16 + lo) * BD + k0]);
            short8 b[4];
#pragma unroll
            for (int n = 0; n < 4; ++n)
                b[n] = *reinterpret_cast<const short8*>(&vT[(wn * 64 + n * 16 + lo) * BD + k0]);
#pragma unroll
            for (int n = 0; n < 4; ++n) {
                accO[0][n] = __builtin_amdgcn_mfma_f32_16x16x32_bf16(a0, b[n], accO[0][n], 0, 0, 0);
                accO[1][n] = __builtin_amdgcn_mfma_f32_16x16x32_bf16(a1, b[n], accO[1][n], 0, 0, 0);
            }
        }
    }

    // ---- out: atomic accumulate across D-chunks ----
#pragma unroll
    for (int m = 0; m < 2; ++m)
#pragma unroll
        for (int n = 0; n < 4; ++n) {
            const int c = wn * 64 + n * 16 + lo;
            if (c < CC) {
#pragma unroll
                for (int r = 0; r < 4; ++r) {
                    const int b_ = bm0 + wm * 32 + m * 16 + hi * 4 + r;
                    atomicAdd(&out[(size_t)b_ * CC + c], accO[m][n][r]);
                }
            }
        }
#undef PHASE_A
}

// ---------------- slow fallback (round-1, passed) ----------------

#define XS_STRIDE 72
#define KS_STRIDE 72
#define KT_STRIDE 72
#define VL_STRIDE 106
#define FKC 64
#define FNKC (KSZ / FKC)

__global__ __launch_bounds__(256)
void varkeys_pre(const float* __restrict__ x, const float* __restrict__ keys,
                 float* __restrict__ kk, float* __restrict__ xx)
{
    const int tid  = threadIdx.x;
    const int wid  = tid >> 6;
    const int lane = tid & 63;
    const int lo   = lane & 15;
    const int sub  = lane >> 4;
    const int row  = blockIdx.x * 16 + wid * 4 + sub;
    const float* src = (row < DSZ) ? keys + (size_t)row * KSZ
                                   : x + (size_t)(row - DSZ) * KSZ;
    float s = 0.f;
#pragma unroll
    for (int j = 0; j < 8; ++j) {
        float4 v = *reinterpret_cast<const float4*>(src + j * 64 + lo * 4);
        s += v.x * v.x + v.y * v.y + v.z * v.z + v.w * v.w;
    }
    s += __shfl_xor(s, 1); s += __shfl_xor(s, 2);
    s += __shfl_xor(s, 4); s += __shfl_xor(s, 8);
    if (lo == 0) {
        if (row < DSZ) kk[row] = s;
        else           xx[row - DSZ] = s;
    }
}

__global__ __launch_bounds__(256, 2)
void varkeys_main(const float* __restrict__ x, const float* __restrict__ keys,
                  const float* __restrict__ values, float* __restrict__ out,
                  const float* __restrict__ kk_ws, const float* __restrict__ xx_ws,
                  int use_ws)
{
    __shared__ __align__(16) u16 xs[BM * XS_STRIDE];
    __shared__ __align__(16) u16 ks[BD * KS_STRIDE];
    __shared__ __align__(16) u16 kT[BM * KT_STRIDE];
    __shared__ __align__(16) u16 vls[BD * VL_STRIDE];
    __shared__ float kk_s[DCHUNK];
    __shared__ float xx_s[BM];

    const int tid  = threadIdx.x;
    const int wid  = tid >> 6;
    const int lane = tid & 63;
    const int lo   = lane & 15;
    const int hi   = lane >> 4;
    const int wm   = wid >> 1;
    const int wn   = wid & 1;
    const int bm0   = blockIdx.x * BM;
    const int dbase = blockIdx.y * DCHUNK;

    if (use_ws) {
        for (int i = tid; i < DCHUNK; i += 256) kk_s[i] = kk_ws[dbase + i];
        if (tid < BM) xx_s[tid] = xx_ws[bm0 + tid];
    } else {
        for (int rbase = wid * 4; rbase < DCHUNK + BM; rbase += 16) {
            const int row = rbase + hi;
            const float* src = (row < DCHUNK)
                ? keys + (size_t)(dbase + row) * KSZ
                : x + (size_t)(bm0 + row - DCHUNK) * KSZ;
            float s = 0.f;
#pragma unroll
            for (int j = 0; j < 8; ++j) {
                float4 v = *reinterpret_cast<const float4*>(src + j * 64 + lo * 4);
                s += v.x * v.x + v.y * v.y + v.z * v.z + v.w * v.w;
            }
            s += __shfl_xor(s, 1); s += __shfl_xor(s, 2);
            s += __shfl_xor(s, 4); s += __shfl_xor(s, 8);
            if (lo == 0) {
                if (row < DCHUNK) kk_s[row] = s;
                else              xx_s[row - DCHUNK] = s;
            }
        }
    }
    __syncthreads();

    f32x4 accO[4][4];
#pragma unroll
    for (int m = 0; m < 4; ++m)
#pragma unroll
        for (int n = 0; n < 4; ++n) accO[m][n] = f32x4{0.f, 0.f, 0.f, 0.f};

    for (int it = 0; it < NITER; ++it) {
        const int d0 = dbase + it * BD;

        f32x4 accS[4][2];
#pragma unroll
        for (int m = 0; m < 4; ++m)
#pragma unroll
            for (int n = 0; n < 2; ++n) accS[m][n] = f32x4{0.f, 0.f, 0.f, 0.f};

        for (int kc = 0; kc < FNKC; ++kc) {
            __syncthreads();
#pragma unroll
            for (int j = 0; j < 8; ++j) {
                const int idx = tid + j * 256;
                const int row = idx >> 4, c4 = idx & 15;
                float4 v = *reinterpret_cast<const float4*>(
                    x + (size_t)(bm0 + row) * KSZ + kc * FKC + c4 * 4);
                u32* dst = reinterpret_cast<u32*>(&xs[row * XS_STRIDE + c4 * 4]);
                dst[0] = pack2(v.x, v.y); dst[1] = pack2(v.z, v.w);
            }
#pragma unroll
            for (int j = 0; j < 4; ++j) {
                const int idx = tid + j * 256;
                const int row = idx >> 4, c4 = idx & 15;
                float4 v = *reinterpret_cast<const float4*>(
                    keys + (size_t)(d0 + row) * KSZ + kc * FKC + c4 * 4);
                u32* dst = reinterpret_cast<u32*>(&ks[row * KS_STRIDE + c4 * 4]);
                dst[0] = pack2(v.x, v.y); dst[1] = pack2(v.z, v.w);
            }
            __syncthreads();
#pragma unroll
            for (int kst = 0; kst < 2; ++kst) {
                const int k0 = kst * 32 + hi * 8;
                short8 a[4], b[2];
#pragma unroll
                for (int m = 0; m < 4; ++m)
                    a[m] = *reinterpret_cast<const short8*>(
                        &xs[(wm * 64 + m * 16 + lo) * XS_STRIDE + k0]);
#pragma unroll
                for (int n = 0; n < 2; ++n)
                    b[n] = *reinterpret_cast<const short8*>(
                        &ks[(wn * 32 + n * 16 + lo) * KS_STRIDE + k0]);
#pragma unroll
                for (int m = 0; m < 4; ++m)
#pragma unroll
                    for (int n = 0; n < 2; ++n)
                        accS[m][n] = __builtin_amdgcn_mfma_f32_16x16x32_bf16(
                            a[m], b[n], accS[m][n], 0, 0, 0);
            }
        }

#pragma unroll
        for (int m = 0; m < 4; ++m)
#pragma unroll
            for (int n = 0; n < 2; ++n) {
                const int dl = wn * 32 + n * 16 + lo;
                const float kkv = kk_s[it * BD + dl];
#pragma unroll
                for (int r = 0; r < 4; ++r) {
                    const int bl = wm * 64 + m * 16 + hi * 4 + r;
                    const float dsq = kkv + xx_s[bl] - 2.f * accS[m][n][r] + EPSV;
                    kT[bl * KT_STRIDE + dl] = f2bf(__builtin_amdgcn_rcpf(dsq));
                }
            }

#pragma unroll
        for (int j = 0; j < 7; ++j) {
            const int idx = tid + j * 256;
            if (idx < 1600) {
                const int row = idx / 25, c4 = idx % 25;
                float4 v = *reinterpret_cast<const float4*>(
                    values + (size_t)(d0 + row) * CC + c4 * 4);
                u32* dst = reinterpret_cast<u32*>(&vls[row * VL_STRIDE + c4 * 4]);
                dst[0] = pack2(v.x, v.y); dst[1] = pack2(v.z, v.w);
            }
        }
        __syncthreads();

#pragma unroll
        for (int ks2 = 0; ks2 < 2; ++ks2) {
            const int k0 = ks2 * 32 + hi * 8;
            short8 a[4], b[4];
#pragma unroll
            for (int m = 0; m < 4; ++m)
                a[m] = *reinterpret_cast<const short8*>(
                    &kT[(wm * 64 + m * 16 + lo) * KT_STRIDE + k0]);
#pragma unroll
            for (int n = 0; n < 4; ++n) {
                const int c = wn * 64 + n * 16 + lo;
                short8 t = {0, 0, 0, 0, 0, 0, 0, 0};
                if (c < CC) {
#pragma unroll
                    for (int i = 0; i < 8; ++i)
                        t[i] = (short)vls[(k0 + i) * VL_STRIDE + c];
                }
                b[n] = t;
            }
#pragma unroll
            for (int m = 0; m < 4; ++m)
#pragma unroll
                for (int n = 0; n < 4; ++n)
                    accO[m][n] = __builtin_amdgcn_mfma_f32_16x16x32_bf16(
                        a[m], b[n], accO[m][n], 0, 0, 0);
        }
    }

#pragma unroll
    for (int m = 0; m < 4; ++m)
#pragma unroll
        for (int n = 0; n < 4; ++n) {
            const int c = wn * 64 + n * 16 + lo;
            if (c < CC) {
#pragma unroll
                for (int r = 0; r < 4; ++r) {
                    const int b_ = bm0 + wm * 64 + m * 16 + hi * 4 + r;
                    atomicAdd(&out[(size_t)b_ * CC + c], accO[m][n][r]);
                }
            }
        }
}

extern "C" void kernel_launch(void* const* d_in, const int* in_sizes, int n_in,
                              void* d_out, int out_size, void* d_ws, size_t ws_size,
                              hipStream_t stream) {
    const float* x      = (const float*)d_in[0];
    const float* keys   = (const float*)d_in[1];
    const float* values = (const float*)d_in[2];
    float* out = (float*)d_out;

    hipMemsetAsync(d_out, 0, (size_t)out_size * sizeof(float), stream);

    // fast-path ws layout
    const size_t off_xw = 0;
    const size_t off_kw = off_xw + (size_t)BSZ * KSZ * 2;   //  4 MB
    const size_t off_vw = off_kw + (size_t)DSZ * KSZ * 2;   // +16 MB
    const size_t off_kk = off_vw + (size_t)CP * DSZ * 2;    //  +4 MB
    const size_t off_xx = off_kk + (size_t)DSZ * 4;
    const size_t need   = off_xx + (size_t)BSZ * 4;         // ~24.1 MB

    if (ws_size >= need) {
        u16* xw = (u16*)((char*)d_ws + off_xw);
        u16* kw = (u16*)((char*)d_ws + off_kw);
        u16* vw = (u16*)((char*)d_ws + off_vw);
        float* kk = (float*)((char*)d_ws + off_kk);
        float* xx = (float*)((char*)d_ws + off_xx);
        convert_xk<<<dim3((DSZ + BSZ) / 4), dim3(256), 0, stream>>>(x, keys, xw, kw, kk, xx);
        convert_v<<<dim3((CP * DSZ / 8) / 256), dim3(256), 0, stream>>>(values, vw);
        varkeys_fast<<<dim3(DSPLIT * (BSZ / BM)), dim3(512), 0, stream>>>(xw, kw, vw, kk, xx, out);
    } else {
        const size_t ws_need = (size_t)(DSZ + BSZ) * sizeof(float);  // 80 KB
        const int use_ws = (ws_size >= ws_need) ? 1 : 0;
        float* kk = (float*)d_ws;
        float* xx = kk + DSZ;
        if (use_ws) {
            varkeys_pre<<<dim3((DSZ + BSZ) / 16), dim3(256), 0, stream>>>(x, keys, kk, xx);
        }
        varkeys_main<<<dim3(BSZ / BM, DSPLIT), dim3(256), 0, stream>>>(
            x, keys, values, out, kk, xx, use_ws);
    }
}

// Round 5
// 134.880 us; speedup vs baseline: 3.6354x; 1.0108x over previous
//
#include <hip/hip_runtime.h>
#include <hip/hip_bf16.h>
#include <cstdint>

// Varkeys: out[b,c] = sum_d values[d,c] / (||k_d||^2 - 2 k_d.x_b + ||x_b||^2 + EPS)
// R5 = R3 (passed, 118us) + ONE change: kT stride 72, linear col indexing both
// sides (kills the measured 8.4e6 bank conflicts from kT epilogue writes).
// x fragments register-resident, keys KC=256 dbuf pipeline with counted vmcnt,
// vT/kk prefetched at it-start, 512 threads, grid = 256 WGs (1/CU).
// B=4096 D=16384 K=512 C=100 (padded 128). bf16 MFMA 16x16x32, fp32 accum.

#define BSZ   4096
#define DSZ   16384
#define KSZ   512
#define CC    100
#define CP    128
#define EPSV  1e-4f

#define BM     128
#define BD     64
#define DSPLIT 8
#define DCHUNK (DSZ / DSPLIT)   // 2048
#define NITER  (DCHUNK / BD)    // 32
#define KC     256              // keys chunk cols; 2 chunks per it
#define KTS    72               // kT row stride in u16 (144B: rotates banks by 16/row-step-4)

typedef short  short8 __attribute__((ext_vector_type(8)));
typedef float  f32x4  __attribute__((ext_vector_type(4)));
typedef unsigned int   u32;
typedef unsigned short u16;

__device__ __forceinline__ u16 f2bf(float f) {
    union { float f; u32 u; } cv; cv.f = f;
    u32 u = cv.u;
    u += 0x7fffu + ((u >> 16) & 1u);   // RNE
    return (u16)(u >> 16);
}
__device__ __forceinline__ u32 pack2(float a, float b) {
    return (u32)f2bf(a) | ((u32)f2bf(b) << 16);
}

__device__ __forceinline__ void gload_lds16(const void* g, void* l) {
    __builtin_amdgcn_global_load_lds(
        (const __attribute__((address_space(1))) u32*)g,
        (__attribute__((address_space(3))) u32*)l, 16, 0, 0);
}

// ---------------- fast-path pre-kernels ----------------

// x,keys -> bf16, swizzled within 64-col chunks by (row&7)<<3; fused row norms.
__global__ __launch_bounds__(256)
void convert_xk(const float* __restrict__ x, const float* __restrict__ keys,
                u16* __restrict__ xw, u16* __restrict__ kw,
                float* __restrict__ kk, float* __restrict__ xx)
{
    const int tid = threadIdx.x, wid = tid >> 6, lane = tid & 63;
    const int row = blockIdx.x * 4 + wid;           // 0..20479
    const float* src; u16* dst; float* nrm; int r;
    if (row < DSZ) { r = row;       src = keys + (size_t)r * KSZ; dst = kw + (size_t)r * KSZ; nrm = kk + r; }
    else           { r = row - DSZ; src = x    + (size_t)r * KSZ; dst = xw + (size_t)r * KSZ; nrm = xx + r; }

    float4 v0 = *reinterpret_cast<const float4*>(src + lane * 8);
    float4 v1 = *reinterpret_cast<const float4*>(src + lane * 8 + 4);
    float s = v0.x*v0.x + v0.y*v0.y + v0.z*v0.z + v0.w*v0.w
            + v1.x*v1.x + v1.y*v1.y + v1.z*v1.z + v1.w*v1.w;

    uint4 w;
    w.x = pack2(v0.x, v0.y); w.y = pack2(v0.z, v0.w);
    w.z = pack2(v1.x, v1.y); w.w = pack2(v1.z, v1.w);
    const int dcol = ((lane >> 3) << 6) + (((lane & 7) ^ (r & 7)) << 3);
    *reinterpret_cast<uint4*>(dst + dcol) = w;

    s += __shfl_xor(s, 1);  s += __shfl_xor(s, 2);  s += __shfl_xor(s, 4);
    s += __shfl_xor(s, 8);  s += __shfl_xor(s, 16); s += __shfl_xor(s, 32);
    if (lane == 0) *nrm = s;
}

// values [D][100] f32 -> vw [128][D] bf16 (transposed, c>=100 zero),
// swizzled within 64-d chunks by (c&7)<<3.
__global__ __launch_bounds__(256)
void convert_v(const float* __restrict__ values, u16* __restrict__ vw)
{
    const int gid = blockIdx.x * 256 + threadIdx.x;   // 0..262143
    const int c = gid >> 11;                          // 0..127
    const int j = gid & 2047;                         // d-group of 8
    const int dp  = ((j >> 3) << 6) + ((j & 7) << 3);
    const int dsg = ((j >> 3) << 6) + (((j & 7) ^ (c & 7)) << 3);
    uint4 w = make_uint4(0, 0, 0, 0);
    if (c < CC) {
        float f[8];
#pragma unroll
        for (int i = 0; i < 8; ++i) f[i] = values[(size_t)(dsg + i) * CC + c];
        w.x = pack2(f[0], f[1]); w.y = pack2(f[2], f[3]);
        w.z = pack2(f[4], f[5]); w.w = pack2(f[6], f[7]);
    }
    *reinterpret_cast<uint4*>(vw + (size_t)c * DSZ + dp) = w;
}

// ---------------- fast main kernel: 512 threads, x in registers ----------------
__global__ __launch_bounds__(512, 2)
void varkeys_fast(const u16* __restrict__ xw, const u16* __restrict__ kw,
                  const u16* __restrict__ vw, const float* __restrict__ kkp,
                  const float* __restrict__ xxp, float* __restrict__ out)
{
    __shared__ __align__(16) u16 ksb0[BD * KC];     // 32KB keys chunk buf 0
    __shared__ __align__(16) u16 ksb1[BD * KC];     // 32KB keys chunk buf 1
    __shared__ __align__(16) u16 kT[BM * KTS];      // 18KB kern tile, stride 72
    __shared__ __align__(16) u16 vT[CP * BD];       // 16KB values^T tile
    __shared__ float xx_s[BM];

    const int tid  = threadIdx.x;
    const int wid  = tid >> 6;     // 0..7
    const int lane = tid & 63;
    const int lo   = lane & 15;
    const int hi   = lane >> 4;
    const int wm   = wid >> 1;     // 0..3 : rows wm*32..+31
    const int wn   = wid & 1;      // phase A: dict half wn*32; phase B: col half wn*64

    // dchunk pinned per XCD (bid%8 == XCD id); 32 b-blocks per dchunk.
    const int h  = blockIdx.x;
    const int by = h & 7, bx = h >> 3;
    const int bm0   = bx * BM;
    const int dbase = by * DCHUNK;

    if (tid < BM) xx_s[tid] = xxp[bm0 + tid];

    // ---- x fragments: 2 m-frags x 16 k-slices, register resident ----
    short8 xf[2][16];
    {
        const int rbase = bm0 + wm * 32 + lo;
#pragma unroll
        for (int m = 0; m < 2; ++m) {
            const int row = rbase + m * 16;
            const size_t roff = (size_t)row * KSZ;
            const int rs = (row & 7) << 3;
#pragma unroll
            for (int t = 0; t < 16; ++t) {
                const int col = (t * 32 + hi * 8) ^ rs;
                xf[m][t] = *reinterpret_cast<const short8*>(xw + roff + col);
            }
        }
    }

    f32x4 accO[2][4];
#pragma unroll
    for (int m = 0; m < 2; ++m)
#pragma unroll
        for (int n = 0; n < 4; ++n) accO[m][n] = f32x4{0.f, 0.f, 0.f, 0.f};

    // prologue: issue ks(it0, chunk0) -> ksb0
#pragma unroll
    for (int i = 0; i < 4; ++i) {
        const int ci = wid * 4 + i, flat = ci * 512 + lane * 8;
        gload_lds16(kw + (size_t)(dbase + (flat >> 8)) * KSZ + (flat & 255),
                    (char*)ksb0 + ci * 1024);
    }
    asm volatile("s_waitcnt lgkmcnt(0)" ::: "memory");   // xx_s visible
    __builtin_amdgcn_s_barrier();

    const int swz = (lo & 7) << 3;

#define PHASE_A(CHUNK, KSBUF)                                                        \
    {                                                                                \
        _Pragma("unroll")                                                            \
        for (int j = 0; j < 8; ++j) {                                                \
            const int k0 = (j * 32 + hi * 8) ^ swz;                                  \
            short8 b0 = *reinterpret_cast<const short8*>(&KSBUF[(wn*32 + lo)*KC + k0]);      \
            short8 b1 = *reinterpret_cast<const short8*>(&KSBUF[(wn*32 + 16 + lo)*KC + k0]); \
            accS[0][0] = __builtin_amdgcn_mfma_f32_16x16x32_bf16(xf[0][(CHUNK)*8+j], b0, accS[0][0], 0,0,0); \
            accS[1][0] = __builtin_amdgcn_mfma_f32_16x16x32_bf16(xf[1][(CHUNK)*8+j], b0, accS[1][0], 0,0,0); \
            accS[0][1] = __builtin_amdgcn_mfma_f32_16x16x32_bf16(xf[0][(CHUNK)*8+j], b1, accS[0][1], 0,0,0); \
            accS[1][1] = __builtin_amdgcn_mfma_f32_16x16x32_bf16(xf[1][(CHUNK)*8+j], b1, accS[1][1], 0,0,0); \
        }                                                                            \
    }

    for (int it = 0; it < NITER; ++it) {
        const int d0 = dbase + it * BD;

        f32x4 accS[2][2];
#pragma unroll
        for (int m = 0; m < 2; ++m)
#pragma unroll
            for (int n = 0; n < 2; ++n) accS[m][n] = f32x4{0.f, 0.f, 0.f, 0.f};

        // ======== even step: compute chunk0 from ksb0 ========
        __builtin_amdgcn_s_barrier();            // protect ksb1 + vT overwrite
        // issue ks(it, chunk1) -> ksb1
#pragma unroll
        for (int i = 0; i < 4; ++i) {
            const int ci = wid * 4 + i, flat = ci * 512 + lane * 8;
            gload_lds16(kw + (size_t)(d0 + (flat >> 8)) * KSZ + KC + (flat & 255),
                        (char*)ksb1 + ci * 1024);
        }
        // issue vT(it)
#pragma unroll
        for (int i = 0; i < 2; ++i) {
            const int ci = wid * 2 + i, flat = ci * 512 + lane * 8;
            gload_lds16(vw + (size_t)(flat >> 6) * DSZ + d0 + (flat & 63),
                        (char*)vT + ci * 1024);
        }
        // kk(it) -> regs (2 VMEM loads, counted in vmcnt)
        const float kkf0 = kkp[d0 + wn * 32 + lo];
        const float kkf1 = kkp[d0 + wn * 32 + 16 + lo];
        asm volatile("s_waitcnt vmcnt(8)" ::: "memory");   // ks(it,chunk0) done
        __builtin_amdgcn_s_barrier();
        __builtin_amdgcn_sched_barrier(0);
        PHASE_A(0, ksb0)

        // ======== odd step: compute chunk1 from ksb1 ========
        __builtin_amdgcn_s_barrier();            // protect ksb0 overwrite
        if (it < NITER - 1) {
            const int nd0 = d0 + BD;
#pragma unroll
            for (int i = 0; i < 4; ++i) {
                const int ci = wid * 4 + i, flat = ci * 512 + lane * 8;
                gload_lds16(kw + (size_t)(nd0 + (flat >> 8)) * KSZ + (flat & 255),
                            (char*)ksb0 + ci * 1024);
            }
            asm volatile("s_waitcnt vmcnt(4)" ::: "memory");  // ks(it,ch1)+vT+kk done
        } else {
            asm volatile("s_waitcnt vmcnt(0)" ::: "memory");
        }
        __builtin_amdgcn_s_barrier();
        __builtin_amdgcn_sched_barrier(0);
        PHASE_A(1, ksb1)

        // ---- epilogue A: kern = rcp(kk - 2S + xx + eps) -> kT (stride 72, linear) ----
#pragma unroll
        for (int m = 0; m < 2; ++m)
#pragma unroll
            for (int n = 0; n < 2; ++n) {
                const int dl = wn * 32 + n * 16 + lo;
                const float kkv = n ? kkf1 : kkf0;
#pragma unroll
                for (int r = 0; r < 4; ++r) {
                    const int rowl = wm * 32 + m * 16 + hi * 4 + r;
                    const float dsq = kkv + xx_s[rowl] - 2.f * accS[m][n][r] + EPSV;
                    kT[rowl * KTS + dl] = f2bf(__builtin_amdgcn_rcpf(dsq));
                }
            }
        asm volatile("s_waitcnt lgkmcnt(0)" ::: "memory");
        __builtin_amdgcn_s_barrier();            // publish kT (ks prefetch stays in flight)
        __builtin_amdgcn_sched_barrier(0);

        // ---- phase B: accO += kern(128x64) . V^T ----
#pragma unroll
        for (int kst = 0; kst < 2; ++kst) {
            const int k0l = kst * 32 + hi * 8;        // linear for kT (stride 72)
            const int k0v = k0l ^ swz;                // swizzled for vT (stride 64)
            short8 a0 = *reinterpret_cast<const short8*>(&kT[(wm * 32 + lo) * KTS + k0l]);
            short8 a1 = *reinterpret_cast<const short8*>(&kT[(wm * 32 + 16 + lo) * KTS + k0l]);
            short8 b[4];
#pragma unroll
            for (int n = 0; n < 4; ++n)
                b[n] = *reinterpret_cast<const short8*>(&vT[(wn * 64 + n * 16 + lo) * BD + k0v]);
#pragma unroll
            for (int n = 0; n < 4; ++n) {
                accO[0][n] = __builtin_amdgcn_mfma_f32_16x16x32_bf16(a0, b[n], accO[0][n], 0, 0, 0);
                accO[1][n] = __builtin_amdgcn_mfma_f32_16x16x32_bf16(a1, b[n], accO[1][n], 0, 0, 0);
            }
        }
    }

    // ---- out: atomic accumulate across D-chunks ----
#pragma unroll
    for (int m = 0; m < 2; ++m)
#pragma unroll
        for (int n = 0; n < 4; ++n) {
            const int c = wn * 64 + n * 16 + lo;
            if (c < CC) {
#pragma unroll
                for (int r = 0; r < 4; ++r) {
                    const int b_ = bm0 + wm * 32 + m * 16 + hi * 4 + r;
                    atomicAdd(&out[(size_t)b_ * CC + c], accO[m][n][r]);
                }
            }
        }
#undef PHASE_A
}

// ---------------- slow fallback (round-1, passed) ----------------

#define XS_STRIDE 72
#define KS_STRIDE 72
#define KT_STRIDE 72
#define VL_STRIDE 106
#define FKC 64
#define FNKC (KSZ / FKC)

__global__ __launch_bounds__(256)
void varkeys_pre(const float* __restrict__ x, const float* __restrict__ keys,
                 float* __restrict__ kk, float* __restrict__ xx)
{
    const int tid  = threadIdx.x;
    const int wid  = tid >> 6;
    const int lane = tid & 63;
    const int lo   = lane & 15;
    const int sub  = lane >> 4;
    const int row  = blockIdx.x * 16 + wid * 4 + sub;
    const float* src = (row < DSZ) ? keys + (size_t)row * KSZ
                                   : x + (size_t)(row - DSZ) * KSZ;
    float s = 0.f;
#pragma unroll
    for (int j = 0; j < 8; ++j) {
        float4 v = *reinterpret_cast<const float4*>(src + j * 64 + lo * 4);
        s += v.x * v.x + v.y * v.y + v.z * v.z + v.w * v.w;
    }
    s += __shfl_xor(s, 1); s += __shfl_xor(s, 2);
    s += __shfl_xor(s, 4); s += __shfl_xor(s, 8);
    if (lo == 0) {
        if (row < DSZ) kk[row] = s;
        else           xx[row - DSZ] = s;
    }
}

__global__ __launch_bounds__(256, 2)
void varkeys_main(const float* __restrict__ x, const float* __restrict__ keys,
                  const float* __restrict__ values, float* __restrict__ out,
                  const float* __restrict__ kk_ws, const float* __restrict__ xx_ws,
                  int use_ws)
{
    __shared__ __align__(16) u16 xs[BM * XS_STRIDE];
    __shared__ __align__(16) u16 ks[BD * KS_STRIDE];
    __shared__ __align__(16) u16 kTf[BM * KT_STRIDE];
    __shared__ __align__(16) u16 vls[BD * VL_STRIDE];
    __shared__ float kk_s[DCHUNK];
    __shared__ float xx_s[BM];

    const int tid  = threadIdx.x;
    const int wid  = tid >> 6;
    const int lane = tid & 63;
    const int lo   = lane & 15;
    const int hi   = lane >> 4;
    const int wm   = wid >> 1;
    const int wn   = wid & 1;
    const int bm0   = blockIdx.x * BM;
    const int dbase = blockIdx.y * DCHUNK;

    if (use_ws) {
        for (int i = tid; i < DCHUNK; i += 256) kk_s[i] = kk_ws[dbase + i];
        if (tid < BM) xx_s[tid] = xx_ws[bm0 + tid];
    } else {
        for (int rbase = wid * 4; rbase < DCHUNK + BM; rbase += 16) {
            const int row = rbase + hi;
            const float* src = (row < DCHUNK)
                ? keys + (size_t)(dbase + row) * KSZ
                : x + (size_t)(bm0 + row - DCHUNK) * KSZ;
            float s = 0.f;
#pragma unroll
            for (int j = 0; j < 8; ++j) {
                float4 v = *reinterpret_cast<const float4*>(src + j * 64 + lo * 4);
                s += v.x * v.x + v.y * v.y + v.z * v.z + v.w * v.w;
            }
            s += __shfl_xor(s, 1); s += __shfl_xor(s, 2);
            s += __shfl_xor(s, 4); s += __shfl_xor(s, 8);
            if (lo == 0) {
                if (row < DCHUNK) kk_s[row] = s;
                else              xx_s[row - DCHUNK] = s;
            }
        }
    }
    __syncthreads();

    f32x4 accO[4][4];
#pragma unroll
    for (int m = 0; m < 4; ++m)
#pragma unroll
        for (int n = 0; n < 4; ++n) accO[m][n] = f32x4{0.f, 0.f, 0.f, 0.f};

    for (int it = 0; it < NITER; ++it) {
        const int d0 = dbase + it * BD;

        f32x4 accS[4][2];
#pragma unroll
        for (int m = 0; m < 4; ++m)
#pragma unroll
            for (int n = 0; n < 2; ++n) accS[m][n] = f32x4{0.f, 0.f, 0.f, 0.f};

        for (int kc = 0; kc < FNKC; ++kc) {
            __syncthreads();
#pragma unroll
            for (int j = 0; j < 8; ++j) {
                const int idx = tid + j * 256;
                const int row = idx >> 4, c4 = idx & 15;
                float4 v = *reinterpret_cast<const float4*>(
                    x + (size_t)(bm0 + row) * KSZ + kc * FKC + c4 * 4);
                u32* dst = reinterpret_cast<u32*>(&xs[row * XS_STRIDE + c4 * 4]);
                dst[0] = pack2(v.x, v.y); dst[1] = pack2(v.z, v.w);
            }
#pragma unroll
            for (int j = 0; j < 4; ++j) {
                const int idx = tid + j * 256;
                const int row = idx >> 4, c4 = idx & 15;
                float4 v = *reinterpret_cast<const float4*>(
                    keys + (size_t)(d0 + row) * KSZ + kc * FKC + c4 * 4);
                u32* dst = reinterpret_cast<u32*>(&ks[row * KS_STRIDE + c4 * 4]);
                dst[0] = pack2(v.x, v.y); dst[1] = pack2(v.z, v.w);
            }
            __syncthreads();
#pragma unroll
            for (int kst = 0; kst < 2; ++kst) {
                const int k0 = kst * 32 + hi * 8;
                short8 a[4], b[2];
#pragma unroll
                for (int m = 0; m < 4; ++m)
                    a[m] = *reinterpret_cast<const short8*>(
                        &xs[(wm * 64 + m * 16 + lo) * XS_STRIDE + k0]);
#pragma unroll
                for (int n = 0; n < 2; ++n)
                    b[n] = *reinterpret_cast<const short8*>(
                        &ks[(wn * 32 + n * 16 + lo) * KS_STRIDE + k0]);
#pragma unroll
                for (int m = 0; m < 4; ++m)
#pragma unroll
                    for (int n = 0; n < 2; ++n)
                        accS[m][n] = __builtin_amdgcn_mfma_f32_16x16x32_bf16(
                            a[m], b[n], accS[m][n], 0, 0, 0);
            }
        }

#pragma unroll
        for (int m = 0; m < 4; ++m)
#pragma unroll
            for (int n = 0; n < 2; ++n) {
                const int dl = wn * 32 + n * 16 + lo;
                const float kkv = kk_s[it * BD + dl];
#pragma unroll
                for (int r = 0; r < 4; ++r) {
                    const int bl = wm * 64 + m * 16 + hi * 4 + r;
                    const float dsq = kkv + xx_s[bl] - 2.f * accS[m][n][r] + EPSV;
                    kTf[bl * KT_STRIDE + dl] = f2bf(__builtin_amdgcn_rcpf(dsq));
                }
            }

#pragma unroll
        for (int j = 0; j < 7; ++j) {
            const int idx = tid + j * 256;
            if (idx < 1600) {
                const int row = idx / 25, c4 = idx % 25;
                float4 v = *reinterpret_cast<const float4*>(
                    values + (size_t)(d0 + row) * CC + c4 * 4);
                u32* dst = reinterpret_cast<u32*>(&vls[row * VL_STRIDE + c4 * 4]);
                dst[0] = pack2(v.x, v.y); dst[1] = pack2(v.z, v.w);
            }
        }
        __syncthreads();

#pragma unroll
        for (int ks2 = 0; ks2 < 2; ++ks2) {
            const int k0 = ks2 * 32 + hi * 8;
            short8 a[4], b[4];
#pragma unroll
            for (int m = 0; m < 4; ++m)
                a[m] = *reinterpret_cast<const short8*>(
                    &kTf[(wm * 64 + m * 16 + lo) * KT_STRIDE + k0]);
#pragma unroll
            for (int n = 0; n < 4; ++n) {
                const int c = wn * 64 + n * 16 + lo;
                short8 t = {0, 0, 0, 0, 0, 0, 0, 0};
                if (c < CC) {
#pragma unroll
                    for (int i = 0; i < 8; ++i)
                        t[i] = (short)vls[(k0 + i) * VL_STRIDE + c];
                }
                b[n] = t;
            }
#pragma unroll
            for (int m = 0; m < 4; ++m)
#pragma unroll
                for (int n = 0; n < 4; ++n)
                    accO[m][n] = __builtin_amdgcn_mfma_f32_16x16x32_bf16(
                        a[m], b[n], accO[m][n], 0, 0, 0);
        }
    }

#pragma unroll
    for (int m = 0; m < 4; ++m)
#pragma unroll
        for (int n = 0; n < 4; ++n) {
            const int c = wn * 64 + n * 16 + lo;
            if (c < CC) {
#pragma unroll
                for (int r = 0; r < 4; ++r) {
                    const int b_ = bm0 + wm * 64 + m * 16 + hi * 4 + r;
                    atomicAdd(&out[(size_t)b_ * CC + c], accO[m][n][r]);
                }
            }
        }
}

extern "C" void kernel_launch(void* const* d_in, const int* in_sizes, int n_in,
                              void* d_out, int out_size, void* d_ws, size_t ws_size,
                              hipStream_t stream) {
    const float* x      = (const float*)d_in[0];
    const float* keys   = (const float*)d_in[1];
    const float* values = (const float*)d_in[2];
    float* out = (float*)d_out;

    hipMemsetAsync(d_out, 0, (size_t)out_size * sizeof(float), stream);

    // fast-path ws layout
    const size_t off_xw = 0;
    const size_t off_kw = off_xw + (size_t)BSZ * KSZ * 2;   //  4 MB
    const size_t off_vw = off_kw + (size_t)DSZ * KSZ * 2;   // +16 MB
    const size_t off_kk = off_vw + (size_t)CP * DSZ * 2;    //  +4 MB
    const size_t off_xx = off_kk + (size_t)DSZ * 4;
    const size_t need   = off_xx + (size_t)BSZ * 4;         // ~24.1 MB

    if (ws_size >= need) {
        u16* xw = (u16*)((char*)d_ws + off_xw);
        u16* kw = (u16*)((char*)d_ws + off_kw);
        u16* vw = (u16*)((char*)d_ws + off_vw);
        float* kk = (float*)((char*)d_ws + off_kk);
        float* xx = (float*)((char*)d_ws + off_xx);
        convert_xk<<<dim3((DSZ + BSZ) / 4), dim3(256), 0, stream>>>(x, keys, xw, kw, kk, xx);
        convert_v<<<dim3((CP * DSZ / 8) / 256), dim3(256), 0, stream>>>(values, vw);
        varkeys_fast<<<dim3(DSPLIT * (BSZ / BM)), dim3(512), 0, stream>>>(xw, kw, vw, kk, xx, out);
    } else {
        const size_t ws_need = (size_t)(DSZ + BSZ) * sizeof(float);  // 80 KB
        const int use_ws = (ws_size >= ws_need) ? 1 : 0;
        float* kk = (float*)d_ws;
        float* xx = kk + DSZ;
        if (use_ws) {
            varkeys_pre<<<dim3((DSZ + BSZ) / 16), dim3(256), 0, stream>>>(x, keys, kk, xx);
        }
        varkeys_main<<<dim3(BSZ / BM, DSPLIT), dim3(256), 0, stream>>>(
            x, keys, values, out, kk, xx, use_ws);
    }
}